// Round 14
// baseline (331.369 us; speedup 1.0000x reference)
//
#include <hip/hip_runtime.h>
#include <hip/hip_bf16.h>

#define N_   4
#define CIN  1024
#define H_   56
#define W_   56
#define HW   3136
#define CB   256
#define KK   9
#define OFFC 18

typedef __attribute__((ext_vector_type(8))) short short8;
typedef __attribute__((ext_vector_type(4))) short short4v;
typedef __attribute__((ext_vector_type(4))) float float4v;
typedef unsigned short ushort_t;

// fp32 -> bf16 round-to-nearest-even
__device__ inline ushort_t bf16_rne(float f) {
    unsigned int u = __float_as_uint(f);
    unsigned int r = (u + 0x7FFFu + ((u >> 16) & 1u)) >> 16;
    return (ushort_t)r;
}
__device__ inline void split_bf16(float f, ushort_t& hi, ushort_t& lo) {
    ushort_t h = bf16_rne(f);
    float hf = __uint_as_float(((unsigned int)h) << 16);
    hi = h;
    lo = bf16_rne(f - hf);
}
__device__ inline short8 ld_frag_lds(const ushort_t* base) {
    short4v a = *(const short4v*)base;
    short4v b = *(const short4v*)(base + 4);
    return __builtin_shufflevector(a, b, 0, 1, 2, 3, 4, 5, 6, 7);
}
// Barrier that does NOT drain vmcnt (keeps prefetch global loads in flight).
__device__ inline void lds_barrier() {
    asm volatile("s_waitcnt lgkmcnt(0)" ::: "memory");
    __builtin_amdgcn_s_barrier();
    __builtin_amdgcn_sched_barrier(0);
}

// ---------------------------------------------------------------------------
// Pack weights.
// ---------------------------------------------------------------------------
__global__ void __launch_bounds__(256) pack_weights_kernel(
    const float* __restrict__ w1, const float* __restrict__ w2,
    const float* __restrict__ w3, const float* __restrict__ w_off,
    ushort_t* __restrict__ w1p, ushort_t* __restrict__ w2p,
    ushort_t* __restrict__ w3p, ushort_t* __restrict__ wofp)
{
    int e = blockIdx.x * 256 + threadIdx.x;
    if (e < 256 * 1024) {
        int o = e >> 10, k = e & 1023;
        ushort_t hi, lo; split_bf16(w1[e], hi, lo);
        w1p[(size_t)(o * 2 + 0) * 1024 + k] = hi;
        w1p[(size_t)(o * 2 + 1) * 1024 + k] = lo;
        return;
    }
    e -= 256 * 1024;
    if (e < 256 * 256 * 9) {
        int o = e / 2304; int rem = e % 2304; int c = rem / 9; int k = rem % 9;
        w2p[(size_t)(k * 256 + o) * 256 + c] = bf16_rne(w2[e]);
        return;
    }
    e -= 256 * 256 * 9;
    if (e < 1024 * 256) {
        int o = e >> 8, k = e & 255;
        ushort_t hi, lo; split_bf16(w3[e], hi, lo);
        w3p[(size_t)(o * 2 + 0) * 256 + k] = hi;
        w3p[(size_t)(o * 2 + 1) * 256 + k] = lo;
        return;
    }
    e -= 1024 * 256;
    if (e < 9 * 32 * 256) {
        int k = e / (32 * 256);
        int rem = e % (32 * 256);
        int m = rem >> 8, c = rem & 255;
        float v = (m < OFFC) ? w_off[((size_t)m * 256 + c) * 9 + k] : 0.f;
        wofp[e] = bf16_rne(v);
    }
}

// ---------------------------------------------------------------------------
// 1x1 conv via MFMA (round-11 verbatim).
// ---------------------------------------------------------------------------
template <int MFRAG, bool RELU, bool RESID>
__global__ void __launch_bounds__(256, 4) conv1x1_mfma_kernel(
    const ushort_t* __restrict__ Wp,   // [M][2][Kdim]
    const float* __restrict__ Xin,     // [n][Kdim][HW]
    const float* __restrict__ bias,    // [M]
    const float* __restrict__ resid,   // [n][M][HW] or null
    float* __restrict__ Cout,          // [n][M][HW]
    int M, int Kdim)
{
    __shared__ ushort_t Bs[64][36];   // [p][k], pad 36

    const int tid  = threadIdx.x;
    const int wave = tid >> 6;
    const int lane = tid & 63;
    const int l15  = lane & 15;
    const int quad = lane >> 4;
    const int pBase = blockIdx.x * 64;
    const int mBase = blockIdx.y * (MFRAG * 64) + wave * (MFRAG * 16);
    const int n     = blockIdx.z;
    const float* Xn = Xin + (size_t)n * Kdim * HW;

    float4v acc[MFRAG][4];
#pragma unroll
    for (int i = 0; i < MFRAG; ++i)
#pragma unroll
        for (int j = 0; j < 4; ++j) acc[i][j] = (float4v)(0.f);

    const int kk = tid >> 3;          // 0..31
    const int pq = (tid & 7) * 8;     // 0..56

    const float* src0 = &Xn[(size_t)kk * HW + pBase + pq];
    float4 c0 = *reinterpret_cast<const float4*>(src0);
    float4 c1 = *reinterpret_cast<const float4*>(src0 + 4);

    for (int k0 = 0; k0 < Kdim; k0 += 32) {
        lds_barrier();
        float vs[8] = {c0.x, c0.y, c0.z, c0.w, c1.x, c1.y, c1.z, c1.w};
#pragma unroll
        for (int j = 0; j < 8; ++j) Bs[pq + j][kk] = bf16_rne(vs[j]);

        short8 ah[MFRAG], al[MFRAG];
#pragma unroll
        for (int mt = 0; mt < MFRAG; ++mt) {
            const ushort_t* arow = Wp +
                ((size_t)(mBase + mt * 16 + l15) * 2) * Kdim + k0 + quad * 8;
            ah[mt] = *(const short8*)(arow);
            al[mt] = *(const short8*)(arow + Kdim);
        }
        if (k0 + 32 < Kdim) {
            const float* src = &Xn[(size_t)(k0 + 32 + kk) * HW + pBase + pq];
            c0 = *reinterpret_cast<const float4*>(src);
            c1 = *reinterpret_cast<const float4*>(src + 4);
        }
        lds_barrier();

        short8 bh[4];
#pragma unroll
        for (int nt = 0; nt < 4; ++nt)
            bh[nt] = ld_frag_lds(&Bs[nt * 16 + l15][quad * 8]);
        __builtin_amdgcn_s_setprio(1);
#pragma unroll
        for (int mt = 0; mt < MFRAG; ++mt)
#pragma unroll
            for (int nt = 0; nt < 4; ++nt) {
                acc[mt][nt] = __builtin_amdgcn_mfma_f32_16x16x32_bf16(
                    ah[mt], bh[nt], acc[mt][nt], 0, 0, 0);
                acc[mt][nt] = __builtin_amdgcn_mfma_f32_16x16x32_bf16(
                    al[mt], bh[nt], acc[mt][nt], 0, 0, 0);
            }
        __builtin_amdgcn_s_setprio(0);
    }

#pragma unroll
    for (int mt = 0; mt < MFRAG; ++mt)
#pragma unroll
        for (int rr = 0; rr < 4; ++rr) {
            int row = mBase + mt * 16 + quad * 4 + rr;
            float bv = bias[row];
#pragma unroll
            for (int nt = 0; nt < 4; ++nt) {
                int col = pBase + nt * 16 + l15;
                size_t idx = ((size_t)n * M + row) * HW + col;
                float v = acc[mt][nt][rr] + bv;
                if (RESID) v += resid[idx];
                if (RELU)  v = fmaxf(v, 0.f);
                Cout[idx] = v;
            }
        }
}

// ---------------------------------------------------------------------------
// Offset conv 3x3 via MFMA — v11 (round-11 verbatim): K-split by 4.
// ---------------------------------------------------------------------------
__global__ void __launch_bounds__(256, 2) offset_mfma_kernel(
    const float* __restrict__ r,        // [n][CB][HW]
    const ushort_t* __restrict__ wofp,  // [9][32][256] bf16
    float* __restrict__ offp)           // [4][n][18][HW] partials
{
    __shared__ float win[32][174];

    const int tid  = threadIdx.x;
    const int h    = blockIdx.x;
    const int kh   = blockIdx.y;
    const int n    = blockIdx.z;
    const int wave = tid >> 6;
    const int lane = tid & 63;
    const int l15  = lane & 15;
    const int quad = lane >> 4;
    const float* rn = r + (size_t)n * CB * HW;
    const int cb0 = kh * 64;

    const int p = wave * 16 + l15;

    float4v acc[2];
    acc[0] = (float4v)(0.f);
    acc[1] = (float4v)(0.f);

    for (int cb = cb0; cb < cb0 + 64; cb += 32) {
        __syncthreads();
        for (int f = tid; f < 32 * 3 * 14; f += 256) {
            int c = f / 42, remf = f % 42, row = remf / 14, x4 = (remf % 14) * 4;
            int yg = h - 1 + row;
            float4 v = {0.f, 0.f, 0.f, 0.f};
            if (yg >= 0 && yg < H_)
                v = *reinterpret_cast<const float4*>(
                    &rn[(size_t)(cb + c) * HW + yg * W_ + x4]);
            *reinterpret_cast<float4*>(&win[c][row * 56 + x4]) = v;
        }
        __syncthreads();

        short8 ahA0, ahA1, ahB0, ahB1;
        {
            const ushort_t* a0 = wofp + (size_t)(0 * 32 + l15) * 256 + cb + quad * 8;
            ahA0 = *(const short8*)a0;
            ahA1 = *(const short8*)(a0 + 16 * 256);
        }
#pragma unroll
        for (int k = 0; k < KK; ++k) {
            if (k + 1 < KK) {
                const ushort_t* a1 = wofp +
                    (size_t)((k + 1) * 32 + l15) * 256 + cb + quad * 8;
                ahB0 = *(const short8*)a1;
                ahB1 = *(const short8*)(a1 + 16 * 256);
            }
            const int ky = k / 3;
            const int dx = (k % 3) - 1;
            int x = p + dx;
            bool pvalid = (p < 56) && (x >= 0) && (x < 56);
            int xc = min(max(x, 0), 55);
            short8 bh;
#pragma unroll
            for (int j = 0; j < 8; ++j) {
                float v = win[quad * 8 + j][ky * 56 + xc];
                bh[j] = (short)bf16_rne(pvalid ? v : 0.f);
            }
            acc[0] = __builtin_amdgcn_mfma_f32_16x16x32_bf16(
                ahA0, bh, acc[0], 0, 0, 0);
            acc[1] = __builtin_amdgcn_mfma_f32_16x16x32_bf16(
                ahA1, bh, acc[1], 0, 0, 0);
            ahA0 = ahB0; ahA1 = ahB1;
        }
    }

    if (p < 56) {
        float* base = offp + (size_t)(kh * N_ + n) * OFFC * HW;
#pragma unroll
        for (int mt = 0; mt < 2; ++mt)
#pragma unroll
            for (int rr = 0; rr < 4; ++rr) {
                int m = mt * 16 + quad * 4 + rr;
                if (m < OFFC)
                    base[(size_t)m * HW + h * W_ + p] = acc[mt][rr];
            }
    }
}

// ---------------------------------------------------------------------------
// Deformable conv via MFMA — v14: build gathers widened to ds_read_b128.
// CSTR 36 (row = 144 B, 16B-aligned -> float4 legal). Build fast path:
// 8 iters x (4 independent b128 corner reads + FMA + 1 b64 Bs-write) =
// 40 LDS ops/owner/chunk (was 80 at b64, 136 at scalar). Same per-channel
// FP expression order -> bitwise-identical. LDS 67.4 KB -> 2 blocks/CU.
// ---------------------------------------------------------------------------
#define TPX   28
#define WROWS 5
#define WCOLS 36
#define WPOS  (WROWS * WCOLS)   // 180
#define CSTR  36
#define WITEMS (32 * WROWS * 9) // 1440 float4 stage items per chunk
#define DBLK  (H_ * 2 * N_)     // 448
#define NCHUNK 8

__global__ void __launch_bounds__(512, 2) deform_mfma_kernel(
    const float* __restrict__ r,      // [n][CB][HW]
    const float* __restrict__ off,    // [4][n][18][HW] partials
    const float* __restrict__ b_off,  // [18]
    const ushort_t* __restrict__ w2p, // [9][256][256] bf16 hi
    const float* __restrict__ b2,
    float* __restrict__ r2)           // [n][CB][HW]
{
    __shared__ __align__(16) float    win[WPOS][CSTR];  // 25920 B
    __shared__ __align__(8)  ushort_t Bs[2][KK][32][36];// 41472 B

    const int tid = threadIdx.x;
    const int bid = blockIdx.x;
    const int swz = (bid & 7) * (DBLK >> 3) + (bid >> 3);
    const int xh  = swz & 1;
    const int h   = (swz >> 1) % H_;
    const int n   = swz / (H_ * 2);
    const int xb  = xh * TPX;
    const float* rn = r + (size_t)n * CB * HW;

    // ---- per-thread build metadata in registers (tid < 288 owns (k,p)) ----
    int   bi0 = 0, bi1 = 0, bi2 = 0, bi3 = 0;
    float bw0 = 0.f, bw1 = 0.f, bw2 = 0.f, bw3 = 0.f;
    int   go0 = 0, go1 = 0, go2 = 0, go3 = 0;
    bool  bfast = true;
    const bool bactive = (tid < 288);
    const int  bk = bactive ? (tid / 32) : 0;
    const int  bp = bactive ? (tid % 32) : 0;
    if (bactive && bp < TPX) {
        int pg = xb + bp;
        size_t iy = (size_t)(2 * bk) * HW + h * W_ + pg;
        size_t ix = (size_t)(2 * bk + 1) * HW + h * W_ + pg;
        const size_t plane = (size_t)N_ * OFFC * HW;
        const float* o0 = off + (size_t)n * OFFC * HW;
        float dy = o0[iy] + o0[plane + iy] + o0[2 * plane + iy] +
                   o0[3 * plane + iy] + b_off[2 * bk];
        float dx = o0[ix] + o0[plane + ix] + o0[2 * plane + ix] +
                   o0[3 * plane + ix] + b_off[2 * bk + 1];
        float ys = (float)(h + (bk / 3) - 1) + dy;
        float xs = (float)(pg + (bk % 3) - 1) + dx;
        float y0f = floorf(ys), x0f = floorf(xs);
        int y0 = (int)y0f, x0 = (int)x0f;
        float wy1 = ys - y0f, wy0 = 1.f - wy1;
        float wx1 = xs - x0f, wx0 = 1.f - wx1;
        int   wid[4]; float wg[4]; int gof[4]; bool fast = true;
#pragma unroll
        for (int u = 0; u < 2; ++u)
#pragma unroll
            for (int vv = 0; vv < 2; ++vv) {
                int yy = y0 + u, xx = x0 + vv;
                bool valid = (yy >= 0) && (yy <= 55) && (xx >= 0) && (xx <= 55);
                float wgt = valid ? (u ? wy1 : wy0) * (vv ? wx1 : wx0) : 0.f;
                int ry = yy - (h - 2);
                int rx = xx - (xb - 4);
                if (wgt != 0.f &&
                    (ry < 0 || ry >= WROWS || rx < 0 || rx >= WCOLS))
                    fast = false;
                int idx = min(max(ry, 0), WROWS - 1) * WCOLS +
                          min(max(rx, 0), WCOLS - 1);
                wid[u * 2 + vv] = idx;
                wg[u * 2 + vv]  = wgt;
                gof[u * 2 + vv] = valid ? (yy * W_ + xx) : 0;
            }
        bfast = fast;
        bi0 = wid[0]; bi1 = wid[1]; bi2 = wid[2]; bi3 = wid[3];
        bw0 = wg[0];  bw1 = wg[1];  bw2 = wg[2];  bw3 = wg[3];
        go0 = gof[0]; go1 = gof[1]; go2 = gof[2]; go3 = gof[3];
    }

    const int wave = tid >> 6;
    const int lane = tid & 63;
    const int l15  = lane & 15;
    const int quad = lane >> 4;
    const int mW   = wave * 32;

    float4v acc[2][2];
#pragma unroll
    for (int i = 0; i < 2; ++i)
#pragma unroll
        for (int j = 0; j < 2; ++j) acc[i][j] = (float4v)(0.f);

    auto wload = [&](int f, int cbg) -> float4 {
        int c = f / 45, remf = f % 45, row = remf / 9, q = remf % 9;
        int yg = min(max(h - 2 + row, 0), H_ - 1);
        int xg = xb - 4 + q * 4;
        const float* src = &rn[(size_t)(cbg + c) * HW + yg * W_];
        float4 v;
        if (xg >= 0 && xg <= W_ - 4) {
            v = *reinterpret_cast<const float4*>(src + xg);
        } else {
            v.x = src[min(max(xg + 0, 0), W_ - 1)];
            v.y = src[min(max(xg + 1, 0), W_ - 1)];
            v.z = src[min(max(xg + 2, 0), W_ - 1)];
            v.w = src[min(max(xg + 3, 0), W_ - 1)];
        }
        return v;
    };
    auto wwrite = [&](float4* pre) {
#pragma unroll
        for (int i = 0; i < 3; ++i) {
            int f = tid + 512 * i;
            if (f < WITEMS) {
                int c = f / 45, remf = f % 45, row = remf / 9, q = remf % 9;
                int pos = row * WCOLS + q * 4;
                float4 v = pre[i];
                win[pos + 0][c] = v.x;
                win[pos + 1][c] = v.y;
                win[pos + 2][c] = v.z;
                win[pos + 3][c] = v.w;
            }
        }
    };
    // ---- build: b128 gathers, 4 channels per iter, 4 independent corners --
    auto build = [&](int cbg, int pb) {
        if (bfast) {
#pragma unroll
            for (int c4 = 0; c4 < 32; c4 += 4) {
                float4 v0 = *(const float4*)&win[bi0][c4];
                float4 v1 = *(const float4*)&win[bi1][c4];
                float4 v2 = *(const float4*)&win[bi2][c4];
                float4 v3 = *(const float4*)&win[bi3][c4];
                float s0 = bw0 * v0.x + bw1 * v1.x + bw2 * v2.x + bw3 * v3.x;
                float s1 = bw0 * v0.y + bw1 * v1.y + bw2 * v2.y + bw3 * v3.y;
                float s2 = bw0 * v0.z + bw1 * v1.z + bw2 * v2.z + bw3 * v3.z;
                float s3 = bw0 * v0.w + bw1 * v1.w + bw2 * v2.w + bw3 * v3.w;
                short4v pk;
                pk[0] = (short)bf16_rne(s0);
                pk[1] = (short)bf16_rne(s1);
                pk[2] = (short)bf16_rne(s2);
                pk[3] = (short)bf16_rne(s3);
                *(short4v*)&Bs[pb][bk][bp][c4] = pk;
            }
        } else {
#pragma unroll
            for (int c4 = 0; c4 < 32; c4 += 4) {
                float s[4];
#pragma unroll
                for (int j = 0; j < 4; ++j) {
                    const float* rc = rn + (size_t)(cbg + c4 + j) * HW;
                    s[j] = bw0 * rc[go0] + bw1 * rc[go1] +
                           bw2 * rc[go2] + bw3 * rc[go3];
                }
                short4v pk;
#pragma unroll
                for (int j = 0; j < 4; ++j) pk[j] = (short)bf16_rne(s[j]);
                *(short4v*)&Bs[pb][bk][bp][c4] = pk;
            }
        }
    };

    // ---- prologue: stage + build chunk 0 ----
    float4 pre[3];
#pragma unroll
    for (int i = 0; i < 3; ++i) {
        int f = tid + 512 * i;
        if (f < WITEMS) pre[i] = wload(f, 0);
    }
    wwrite(pre);
#pragma unroll
    for (int i = 0; i < 3; ++i) {
        int f = tid + 512 * i;
        if (f < WITEMS) pre[i] = wload(f, 32);
    }
    lds_barrier();              // win(0) visible
    if (bactive) build(0, 0);
    lds_barrier();              // Bs[0] visible

    for (int ci = 0; ci < NCHUNK; ++ci) {
        const int cb = ci * 32;
        const bool hasNext = (ci + 1 < NCHUNK);
        if (hasNext) {
            wwrite(pre);        // win(ci+1); pre-data loaded 1 chunk ago
            if (ci + 2 < NCHUNK) {
#pragma unroll
                for (int i = 0; i < 3; ++i) {
                    int f = tid + 512 * i;
                    if (f < WITEMS) pre[i] = wload(f, cb + 64);
                }
            }
            lds_barrier();      // barA: win(ci+1) visible
            if (bactive) build(cb + 32, (ci + 1) & 1);
        }

        // ---- MFMA(ci) from Bs[ci&1], concurrent with build(ci+1) ----
        const ushort_t* bsb = &Bs[ci & 1][0][0][0];
        __builtin_amdgcn_s_setprio(1);
#pragma unroll
        for (int k = 0; k < KK; ++k) {
            short8 ah[2];
#pragma unroll
            for (int mt = 0; mt < 2; ++mt) {
                const ushort_t* arow = w2p +
                    (size_t)(k * 256 + (mW + mt * 16 + l15)) * 256 +
                    cb + quad * 8;
                ah[mt] = *(const short8*)(arow);
            }
            short8 bh[2];
#pragma unroll
            for (int nt = 0; nt < 2; ++nt)
                bh[nt] = ld_frag_lds(bsb + ((size_t)k * 32 +
                         nt * 16 + l15) * 36 + quad * 8);
#pragma unroll
            for (int mt = 0; mt < 2; ++mt)
#pragma unroll
                for (int nt = 0; nt < 2; ++nt)
                    acc[mt][nt] = __builtin_amdgcn_mfma_f32_16x16x32_bf16(
                        ah[mt], bh[nt], acc[mt][nt], 0, 0, 0);
        }
        __builtin_amdgcn_s_setprio(0);
        if (hasNext) lds_barrier();   // barB: build(ci+1) complete
    }

    // ---- epilogue: bias + relu ----
#pragma unroll
    for (int mt = 0; mt < 2; ++mt)
#pragma unroll
        for (int rr = 0; rr < 4; ++rr) {
            int o = mW + mt * 16 + quad * 4 + rr;
            float bv = b2[o];
#pragma unroll
            for (int nt = 0; nt < 2; ++nt) {
                int p = nt * 16 + l15;
                if (p < TPX) {
                    float v = fmaxf(acc[mt][nt][rr] + bv, 0.f);
                    r2[((size_t)n * CB + o) * HW + h * W_ + xb + p] = v;
                }
            }
        }
}

// ---------------------------------------------------------------------------
// kernel_launch
// ---------------------------------------------------------------------------
extern "C" void kernel_launch(void* const* d_in, const int* in_sizes, int n_in,
                              void* d_out, int out_size, void* d_ws, size_t ws_size,
                              hipStream_t stream)
{
    const float* x     = (const float*)d_in[0];
    const float* w1    = (const float*)d_in[1];
    const float* b1    = (const float*)d_in[2];
    const float* w_off = (const float*)d_in[3];
    const float* b_off = (const float*)d_in[4];
    const float* w2    = (const float*)d_in[5];
    const float* b2    = (const float*)d_in[6];
    const float* w3    = (const float*)d_in[7];
    const float* b3    = (const float*)d_in[8];
    float* out = (float*)d_out;

    float* ws  = (float*)d_ws;
    float* r    = ws;                             // 3,211,264 f
    float* r2   = r  + (size_t)N_ * CB * HW;      // 3,211,264 f
    float* offb = r2 + (size_t)N_ * CB * HW;      // 4 x 225,792 f (K-split)
    ushort_t* w1p  = (ushort_t*)(offb + (size_t)4 * N_ * OFFC * HW);
    ushort_t* w2p  = w1p + (size_t)256 * 2 * 1024;
    ushort_t* w3p  = w2p + (size_t)9 * 256 * 256;
    ushort_t* wofp = w3p + (size_t)1024 * 2 * 256;

    // 1) pack weights
    {
        int total = 256 * 1024 + 256 * 256 * 9 + 1024 * 256 + 9 * 32 * 256;
        pack_weights_kernel<<<(total + 255) / 256, 256, 0, stream>>>(
            w1, w2, w3, w_off, w1p, w2p, w3p, wofp);
    }
    // 2) r = relu(w1 . x + b1)    M=256, K=1024   (MFRAG=1: 784 blocks)
    {
        dim3 grid(HW / 64, CB / 64, N_);
        conv1x1_mfma_kernel<1, true, false><<<grid, 256, 0, stream>>>(
            w1p, x, b1, nullptr, r, CB, CIN);
    }
    // 3) offp[kh] = conv3x3(r[kh-quarter], w_off)  partials, K-split x4
    {
        dim3 grid(H_, 4, N_);
        offset_mfma_kernel<<<grid, 256, 0, stream>>>(r, wofp, offb);
    }
    // 4) r2 = relu(deform(r, sum(offp)+b_off) . w2 + b2)
    {
        deform_mfma_kernel<<<DBLK, 512, 0, stream>>>(
            r, offb, b_off, w2p, b2, r2);
    }
    // 5) out = relu(x + w3 . r2 + b3)   M=1024, K=256
    {
        dim3 grid(HW / 64, CIN / 128, N_);
        conv1x1_mfma_kernel<2, true, true><<<grid, 256, 0, stream>>>(
            w3p, r2, b3, x, out, CIN, CB);
    }
}

// Round 15
// 320.761 us; speedup vs baseline: 1.0331x; 1.0331x over previous
//
#include <hip/hip_runtime.h>
#include <hip/hip_bf16.h>

#define N_   4
#define CIN  1024
#define H_   56
#define W_   56
#define HW   3136
#define CB   256
#define KK   9
#define OFFC 18

typedef __attribute__((ext_vector_type(8))) short short8;
typedef __attribute__((ext_vector_type(4))) short short4v;
typedef __attribute__((ext_vector_type(4))) float float4v;
typedef unsigned short ushort_t;

// fp32 -> bf16 round-to-nearest-even
__device__ inline ushort_t bf16_rne(float f) {
    unsigned int u = __float_as_uint(f);
    unsigned int r = (u + 0x7FFFu + ((u >> 16) & 1u)) >> 16;
    return (ushort_t)r;
}
__device__ inline void split_bf16(float f, ushort_t& hi, ushort_t& lo) {
    ushort_t h = bf16_rne(f);
    float hf = __uint_as_float(((unsigned int)h) << 16);
    hi = h;
    lo = bf16_rne(f - hf);
}
__device__ inline short8 ld_frag_lds(const ushort_t* base) {
    short4v a = *(const short4v*)base;
    short4v b = *(const short4v*)(base + 4);
    return __builtin_shufflevector(a, b, 0, 1, 2, 3, 4, 5, 6, 7);
}
// Barrier that does NOT drain vmcnt (keeps prefetch global loads in flight).
__device__ inline void lds_barrier() {
    asm volatile("s_waitcnt lgkmcnt(0)" ::: "memory");
    __builtin_amdgcn_s_barrier();
    __builtin_amdgcn_sched_barrier(0);
}

// ---------------------------------------------------------------------------
// Pack weights.
// ---------------------------------------------------------------------------
__global__ void __launch_bounds__(256) pack_weights_kernel(
    const float* __restrict__ w1, const float* __restrict__ w2,
    const float* __restrict__ w3, const float* __restrict__ w_off,
    ushort_t* __restrict__ w1p, ushort_t* __restrict__ w2p,
    ushort_t* __restrict__ w3p, ushort_t* __restrict__ wofp)
{
    int e = blockIdx.x * 256 + threadIdx.x;
    if (e < 256 * 1024) {
        int o = e >> 10, k = e & 1023;
        ushort_t hi, lo; split_bf16(w1[e], hi, lo);
        w1p[(size_t)(o * 2 + 0) * 1024 + k] = hi;
        w1p[(size_t)(o * 2 + 1) * 1024 + k] = lo;
        return;
    }
    e -= 256 * 1024;
    if (e < 256 * 256 * 9) {
        int o = e / 2304; int rem = e % 2304; int c = rem / 9; int k = rem % 9;
        w2p[(size_t)(k * 256 + o) * 256 + c] = bf16_rne(w2[e]);
        return;
    }
    e -= 256 * 256 * 9;
    if (e < 1024 * 256) {
        int o = e >> 8, k = e & 255;
        ushort_t hi, lo; split_bf16(w3[e], hi, lo);
        w3p[(size_t)(o * 2 + 0) * 256 + k] = hi;
        w3p[(size_t)(o * 2 + 1) * 256 + k] = lo;
        return;
    }
    e -= 1024 * 256;
    if (e < 9 * 32 * 256) {
        int k = e / (32 * 256);
        int rem = e % (32 * 256);
        int m = rem >> 8, c = rem & 255;
        float v = (m < OFFC) ? w_off[((size_t)m * 256 + c) * 9 + k] : 0.f;
        wofp[e] = bf16_rne(v);
    }
}

// ---------------------------------------------------------------------------
// 1x1 conv via MFMA (round-11 verbatim).
// ---------------------------------------------------------------------------
template <int MFRAG, bool RELU, bool RESID>
__global__ void __launch_bounds__(256, 4) conv1x1_mfma_kernel(
    const ushort_t* __restrict__ Wp,   // [M][2][Kdim]
    const float* __restrict__ Xin,     // [n][Kdim][HW]
    const float* __restrict__ bias,    // [M]
    const float* __restrict__ resid,   // [n][M][HW] or null
    float* __restrict__ Cout,          // [n][M][HW]
    int M, int Kdim)
{
    __shared__ ushort_t Bs[64][36];   // [p][k], pad 36

    const int tid  = threadIdx.x;
    const int wave = tid >> 6;
    const int lane = tid & 63;
    const int l15  = lane & 15;
    const int quad = lane >> 4;
    const int pBase = blockIdx.x * 64;
    const int mBase = blockIdx.y * (MFRAG * 64) + wave * (MFRAG * 16);
    const int n     = blockIdx.z;
    const float* Xn = Xin + (size_t)n * Kdim * HW;

    float4v acc[MFRAG][4];
#pragma unroll
    for (int i = 0; i < MFRAG; ++i)
#pragma unroll
        for (int j = 0; j < 4; ++j) acc[i][j] = (float4v)(0.f);

    const int kk = tid >> 3;          // 0..31
    const int pq = (tid & 7) * 8;     // 0..56

    const float* src0 = &Xn[(size_t)kk * HW + pBase + pq];
    float4 c0 = *reinterpret_cast<const float4*>(src0);
    float4 c1 = *reinterpret_cast<const float4*>(src0 + 4);

    for (int k0 = 0; k0 < Kdim; k0 += 32) {
        lds_barrier();
        float vs[8] = {c0.x, c0.y, c0.z, c0.w, c1.x, c1.y, c1.z, c1.w};
#pragma unroll
        for (int j = 0; j < 8; ++j) Bs[pq + j][kk] = bf16_rne(vs[j]);

        short8 ah[MFRAG], al[MFRAG];
#pragma unroll
        for (int mt = 0; mt < MFRAG; ++mt) {
            const ushort_t* arow = Wp +
                ((size_t)(mBase + mt * 16 + l15) * 2) * Kdim + k0 + quad * 8;
            ah[mt] = *(const short8*)(arow);
            al[mt] = *(const short8*)(arow + Kdim);
        }
        if (k0 + 32 < Kdim) {
            const float* src = &Xn[(size_t)(k0 + 32 + kk) * HW + pBase + pq];
            c0 = *reinterpret_cast<const float4*>(src);
            c1 = *reinterpret_cast<const float4*>(src + 4);
        }
        lds_barrier();

        short8 bh[4];
#pragma unroll
        for (int nt = 0; nt < 4; ++nt)
            bh[nt] = ld_frag_lds(&Bs[nt * 16 + l15][quad * 8]);
        __builtin_amdgcn_s_setprio(1);
#pragma unroll
        for (int mt = 0; mt < MFRAG; ++mt)
#pragma unroll
            for (int nt = 0; nt < 4; ++nt) {
                acc[mt][nt] = __builtin_amdgcn_mfma_f32_16x16x32_bf16(
                    ah[mt], bh[nt], acc[mt][nt], 0, 0, 0);
                acc[mt][nt] = __builtin_amdgcn_mfma_f32_16x16x32_bf16(
                    al[mt], bh[nt], acc[mt][nt], 0, 0, 0);
            }
        __builtin_amdgcn_s_setprio(0);
    }

#pragma unroll
    for (int mt = 0; mt < MFRAG; ++mt)
#pragma unroll
        for (int rr = 0; rr < 4; ++rr) {
            int row = mBase + mt * 16 + quad * 4 + rr;
            float bv = bias[row];
#pragma unroll
            for (int nt = 0; nt < 4; ++nt) {
                int col = pBase + nt * 16 + l15;
                size_t idx = ((size_t)n * M + row) * HW + col;
                float v = acc[mt][nt][rr] + bv;
                if (RESID) v += resid[idx];
                if (RELU)  v = fmaxf(v, 0.f);
                Cout[idx] = v;
            }
        }
}

// ---------------------------------------------------------------------------
// Offset conv 3x3 via MFMA — v11 (round-11 verbatim): K-split by 4.
// ---------------------------------------------------------------------------
__global__ void __launch_bounds__(256, 2) offset_mfma_kernel(
    const float* __restrict__ r,        // [n][CB][HW]
    const ushort_t* __restrict__ wofp,  // [9][32][256] bf16
    float* __restrict__ offp)           // [4][n][18][HW] partials
{
    __shared__ float win[32][174];

    const int tid  = threadIdx.x;
    const int h    = blockIdx.x;
    const int kh   = blockIdx.y;
    const int n    = blockIdx.z;
    const int wave = tid >> 6;
    const int lane = tid & 63;
    const int l15  = lane & 15;
    const int quad = lane >> 4;
    const float* rn = r + (size_t)n * CB * HW;
    const int cb0 = kh * 64;

    const int p = wave * 16 + l15;

    float4v acc[2];
    acc[0] = (float4v)(0.f);
    acc[1] = (float4v)(0.f);

    for (int cb = cb0; cb < cb0 + 64; cb += 32) {
        __syncthreads();
        for (int f = tid; f < 32 * 3 * 14; f += 256) {
            int c = f / 42, remf = f % 42, row = remf / 14, x4 = (remf % 14) * 4;
            int yg = h - 1 + row;
            float4 v = {0.f, 0.f, 0.f, 0.f};
            if (yg >= 0 && yg < H_)
                v = *reinterpret_cast<const float4*>(
                    &rn[(size_t)(cb + c) * HW + yg * W_ + x4]);
            *reinterpret_cast<float4*>(&win[c][row * 56 + x4]) = v;
        }
        __syncthreads();

        short8 ahA0, ahA1, ahB0, ahB1;
        {
            const ushort_t* a0 = wofp + (size_t)(0 * 32 + l15) * 256 + cb + quad * 8;
            ahA0 = *(const short8*)a0;
            ahA1 = *(const short8*)(a0 + 16 * 256);
        }
#pragma unroll
        for (int k = 0; k < KK; ++k) {
            if (k + 1 < KK) {
                const ushort_t* a1 = wofp +
                    (size_t)((k + 1) * 32 + l15) * 256 + cb + quad * 8;
                ahB0 = *(const short8*)a1;
                ahB1 = *(const short8*)(a1 + 16 * 256);
            }
            const int ky = k / 3;
            const int dx = (k % 3) - 1;
            int x = p + dx;
            bool pvalid = (p < 56) && (x >= 0) && (x < 56);
            int xc = min(max(x, 0), 55);
            short8 bh;
#pragma unroll
            for (int j = 0; j < 8; ++j) {
                float v = win[quad * 8 + j][ky * 56 + xc];
                bh[j] = (short)bf16_rne(pvalid ? v : 0.f);
            }
            acc[0] = __builtin_amdgcn_mfma_f32_16x16x32_bf16(
                ahA0, bh, acc[0], 0, 0, 0);
            acc[1] = __builtin_amdgcn_mfma_f32_16x16x32_bf16(
                ahA1, bh, acc[1], 0, 0, 0);
            ahA0 = ahB0; ahA1 = ahB1;
        }
    }

    if (p < 56) {
        float* base = offp + (size_t)(kh * N_ + n) * OFFC * HW;
#pragma unroll
        for (int mt = 0; mt < 2; ++mt)
#pragma unroll
            for (int rr = 0; rr < 4; ++rr) {
                int m = mt * 16 + quad * 4 + rr;
                if (m < OFFC)
                    base[(size_t)m * HW + h * W_ + p] = acc[mt][rr];
            }
    }
}

// ---------------------------------------------------------------------------
// Deformable conv via MFMA — v15: round-13 b64 build (CSTR=34, 2-way-free
// banking) with build parallelism DOUBLED: 504 owners = 9 taps x 28 real
// positions x 2 channel-halves; each gathers 16 channels = 8 iters x
// (4 independent b64 reads + 1 u32 write) = 40 LDS ops/owner/chunk (was 80
// on 288 owners). Build now spans all 8 waves (~0.57 chunk-units each).
// Pad rows p=28..31 of both Bs buffers pre-zeroed ONCE in the prologue
// (zero bits == bf16_rne(0) -> bitwise-identical output).
// ---------------------------------------------------------------------------
#define TPX   28
#define WROWS 5
#define WCOLS 36
#define WPOS  (WROWS * WCOLS)   // 180
#define CSTR  34
#define WITEMS (32 * WROWS * 9) // 1440 float4 stage items per chunk
#define DBLK  (H_ * 2 * N_)     // 448
#define NCHUNK 8

__global__ void __launch_bounds__(512, 2) deform_mfma_kernel(
    const float* __restrict__ r,      // [n][CB][HW]
    const float* __restrict__ off,    // [4][n][18][HW] partials
    const float* __restrict__ b_off,  // [18]
    const ushort_t* __restrict__ w2p, // [9][256][256] bf16 hi
    const float* __restrict__ b2,
    float* __restrict__ r2)           // [n][CB][HW]
{
    __shared__ __align__(8) float    win[WPOS][CSTR];  // 24480 B
    __shared__ __align__(8) ushort_t Bs[2][KK][32][36];// 41472 B

    const int tid = threadIdx.x;
    const int bid = blockIdx.x;
    const int swz = (bid & 7) * (DBLK >> 3) + (bid >> 3);
    const int xh  = swz & 1;
    const int h   = (swz >> 1) % H_;
    const int n   = swz / (H_ * 2);
    const int xb  = xh * TPX;
    const float* rn = r + (size_t)n * CB * HW;

    // ---- owner mapping: tid < 504 owns (tap bk, pos bp, channel-half) ----
    int   bi0 = 0, bi1 = 0, bi2 = 0, bi3 = 0;
    float bw0 = 0.f, bw1 = 0.f, bw2 = 0.f, bw3 = 0.f;
    int   go0 = 0, go1 = 0, go2 = 0, go3 = 0;
    bool  bfast = true;
    const bool bactive = (tid < KK * TPX * 2);          // 504
    const int  bk    = bactive ? (tid / (TPX * 2)) : 0; // tap 0..8
    const int  bp    = bactive ? ((tid % (TPX * 2)) % TPX) : 0; // pos 0..27
    const int  cbase = bactive ? (((tid % (TPX * 2)) / TPX) * 16) : 0;
    if (bactive) {
        int pg = xb + bp;
        size_t iy = (size_t)(2 * bk) * HW + h * W_ + pg;
        size_t ix = (size_t)(2 * bk + 1) * HW + h * W_ + pg;
        const size_t plane = (size_t)N_ * OFFC * HW;
        const float* o0 = off + (size_t)n * OFFC * HW;
        float dy = o0[iy] + o0[plane + iy] + o0[2 * plane + iy] +
                   o0[3 * plane + iy] + b_off[2 * bk];
        float dx = o0[ix] + o0[plane + ix] + o0[2 * plane + ix] +
                   o0[3 * plane + ix] + b_off[2 * bk + 1];
        float ys = (float)(h + (bk / 3) - 1) + dy;
        float xs = (float)(pg + (bk % 3) - 1) + dx;
        float y0f = floorf(ys), x0f = floorf(xs);
        int y0 = (int)y0f, x0 = (int)x0f;
        float wy1 = ys - y0f, wy0 = 1.f - wy1;
        float wx1 = xs - x0f, wx0 = 1.f - wx1;
        int   wid[4]; float wg[4]; int gof[4]; bool fast = true;
#pragma unroll
        for (int u = 0; u < 2; ++u)
#pragma unroll
            for (int vv = 0; vv < 2; ++vv) {
                int yy = y0 + u, xx = x0 + vv;
                bool valid = (yy >= 0) && (yy <= 55) && (xx >= 0) && (xx <= 55);
                float wgt = valid ? (u ? wy1 : wy0) * (vv ? wx1 : wx0) : 0.f;
                int ry = yy - (h - 2);
                int rx = xx - (xb - 4);
                if (wgt != 0.f &&
                    (ry < 0 || ry >= WROWS || rx < 0 || rx >= WCOLS))
                    fast = false;
                int idx = min(max(ry, 0), WROWS - 1) * WCOLS +
                          min(max(rx, 0), WCOLS - 1);
                wid[u * 2 + vv] = idx;
                wg[u * 2 + vv]  = wgt;
                gof[u * 2 + vv] = valid ? (yy * W_ + xx) : 0;
            }
        bfast = fast;
        bi0 = wid[0]; bi1 = wid[1]; bi2 = wid[2]; bi3 = wid[3];
        bw0 = wg[0];  bw1 = wg[1];  bw2 = wg[2];  bw3 = wg[3];
        go0 = gof[0]; go1 = gof[1]; go2 = gof[2]; go3 = gof[3];
    }

    const int wave = tid >> 6;
    const int lane = tid & 63;
    const int l15  = lane & 15;
    const int quad = lane >> 4;
    const int mW   = wave * 32;

    float4v acc[2][2];
#pragma unroll
    for (int i = 0; i < 2; ++i)
#pragma unroll
        for (int j = 0; j < 2; ++j) acc[i][j] = (float4v)(0.f);

    auto wload = [&](int f, int cbg) -> float4 {
        int c = f / 45, remf = f % 45, row = remf / 9, q = remf % 9;
        int yg = min(max(h - 2 + row, 0), H_ - 1);
        int xg = xb - 4 + q * 4;
        const float* src = &rn[(size_t)(cbg + c) * HW + yg * W_];
        float4 v;
        if (xg >= 0 && xg <= W_ - 4) {
            v = *reinterpret_cast<const float4*>(src + xg);
        } else {
            v.x = src[min(max(xg + 0, 0), W_ - 1)];
            v.y = src[min(max(xg + 1, 0), W_ - 1)];
            v.z = src[min(max(xg + 2, 0), W_ - 1)];
            v.w = src[min(max(xg + 3, 0), W_ - 1)];
        }
        return v;
    };
    auto wwrite = [&](float4* pre) {
#pragma unroll
        for (int i = 0; i < 3; ++i) {
            int f = tid + 512 * i;
            if (f < WITEMS) {
                int c = f / 45, remf = f % 45, row = remf / 9, q = remf % 9;
                int pos = row * WCOLS + q * 4;
                float4 v = pre[i];
                win[pos + 0][c] = v.x;
                win[pos + 1][c] = v.y;
                win[pos + 2][c] = v.z;
                win[pos + 3][c] = v.w;
            }
        }
    };
    // ---- build: 16 channels per owner, b64 gathers (round-13 banking) ----
    auto build = [&](int cbg, int pb) {
        if (bfast) {
#pragma unroll
            for (int c2 = 0; c2 < 16; c2 += 2) {
                int c = cbase + c2;
                float2 v0 = *(const float2*)&win[bi0][c];
                float2 v1 = *(const float2*)&win[bi1][c];
                float2 v2 = *(const float2*)&win[bi2][c];
                float2 v3 = *(const float2*)&win[bi3][c];
                float s0 = bw0 * v0.x + bw1 * v1.x + bw2 * v2.x + bw3 * v3.x;
                float s1 = bw0 * v0.y + bw1 * v1.y + bw2 * v2.y + bw3 * v3.y;
                unsigned int pk = (unsigned int)bf16_rne(s0) |
                                  ((unsigned int)bf16_rne(s1) << 16);
                *(unsigned int*)&Bs[pb][bk][bp][c] = pk;
            }
        } else {
#pragma unroll
            for (int c4 = 0; c4 < 16; c4 += 4) {
                int c = cbase + c4;
                float s[4];
#pragma unroll
                for (int j = 0; j < 4; ++j) {
                    const float* rc = rn + (size_t)(cbg + c + j) * HW;
                    s[j] = bw0 * rc[go0] + bw1 * rc[go1] +
                           bw2 * rc[go2] + bw3 * rc[go3];
                }
                short4v pk;
#pragma unroll
                for (int j = 0; j < 4; ++j) pk[j] = (short)bf16_rne(s[j]);
                *(short4v*)&Bs[pb][bk][bp][c] = pk;
            }
        }
    };

    // ---- prologue: zero Bs pad rows (once), stage + build chunk 0 ----
    for (int e = tid; e < 2 * KK * 4 * 18; e += 512) {
        int b = e / (KK * 4 * 18);
        int rem = e % (KK * 4 * 18);
        int k = rem / (4 * 18);
        int rem2 = rem % (4 * 18);
        int rr = rem2 / 18;
        int w = rem2 % 18;
        *(unsigned int*)&Bs[b][k][28 + rr][w * 2] = 0u;
    }
    float4 pre[3];
#pragma unroll
    for (int i = 0; i < 3; ++i) {
        int f = tid + 512 * i;
        if (f < WITEMS) pre[i] = wload(f, 0);
    }
    wwrite(pre);
#pragma unroll
    for (int i = 0; i < 3; ++i) {
        int f = tid + 512 * i;
        if (f < WITEMS) pre[i] = wload(f, 32);
    }
    lds_barrier();              // win(0) + pad zeros visible
    if (bactive) build(0, 0);
    lds_barrier();              // Bs[0] visible

    for (int ci = 0; ci < NCHUNK; ++ci) {
        const int cb = ci * 32;
        const bool hasNext = (ci + 1 < NCHUNK);
        if (hasNext) {
            wwrite(pre);        // win(ci+1); pre-data loaded 1 chunk ago
            if (ci + 2 < NCHUNK) {
#pragma unroll
                for (int i = 0; i < 3; ++i) {
                    int f = tid + 512 * i;
                    if (f < WITEMS) pre[i] = wload(f, cb + 64);
                }
            }
            lds_barrier();      // barA: win(ci+1) visible
            if (bactive) build(cb + 32, (ci + 1) & 1);
        }

        // ---- MFMA(ci) from Bs[ci&1], concurrent with build(ci+1) ----
        const ushort_t* bsb = &Bs[ci & 1][0][0][0];
        __builtin_amdgcn_s_setprio(1);
#pragma unroll
        for (int k = 0; k < KK; ++k) {
            short8 ah[2];
#pragma unroll
            for (int mt = 0; mt < 2; ++mt) {
                const ushort_t* arow = w2p +
                    (size_t)(k * 256 + (mW + mt * 16 + l15)) * 256 +
                    cb + quad * 8;
                ah[mt] = *(const short8*)(arow);
            }
            short8 bh[2];
#pragma unroll
            for (int nt = 0; nt < 2; ++nt)
                bh[nt] = ld_frag_lds(bsb + ((size_t)k * 32 +
                         nt * 16 + l15) * 36 + quad * 8);
#pragma unroll
            for (int mt = 0; mt < 2; ++mt)
#pragma unroll
                for (int nt = 0; nt < 2; ++nt)
                    acc[mt][nt] = __builtin_amdgcn_mfma_f32_16x16x32_bf16(
                        ah[mt], bh[nt], acc[mt][nt], 0, 0, 0);
        }
        __builtin_amdgcn_s_setprio(0);
        if (hasNext) lds_barrier();   // barB: build(ci+1) complete
    }

    // ---- epilogue: bias + relu ----
#pragma unroll
    for (int mt = 0; mt < 2; ++mt)
#pragma unroll
        for (int rr = 0; rr < 4; ++rr) {
            int o = mW + mt * 16 + quad * 4 + rr;
            float bv = b2[o];
#pragma unroll
            for (int nt = 0; nt < 2; ++nt) {
                int p = nt * 16 + l15;
                if (p < TPX) {
                    float v = fmaxf(acc[mt][nt][rr] + bv, 0.f);
                    r2[((size_t)n * CB + o) * HW + h * W_ + xb + p] = v;
                }
            }
        }
}

// ---------------------------------------------------------------------------
// kernel_launch
// ---------------------------------------------------------------------------
extern "C" void kernel_launch(void* const* d_in, const int* in_sizes, int n_in,
                              void* d_out, int out_size, void* d_ws, size_t ws_size,
                              hipStream_t stream)
{
    const float* x     = (const float*)d_in[0];
    const float* w1    = (const float*)d_in[1];
    const float* b1    = (const float*)d_in[2];
    const float* w_off = (const float*)d_in[3];
    const float* b_off = (const float*)d_in[4];
    const float* w2    = (const float*)d_in[5];
    const float* b2    = (const float*)d_in[6];
    const float* w3    = (const float*)d_in[7];
    const float* b3    = (const float*)d_in[8];
    float* out = (float*)d_out;

    float* ws  = (float*)d_ws;
    float* r    = ws;                             // 3,211,264 f
    float* r2   = r  + (size_t)N_ * CB * HW;      // 3,211,264 f
    float* offb = r2 + (size_t)N_ * CB * HW;      // 4 x 225,792 f (K-split)
    ushort_t* w1p  = (ushort_t*)(offb + (size_t)4 * N_ * OFFC * HW);
    ushort_t* w2p  = w1p + (size_t)256 * 2 * 1024;
    ushort_t* w3p  = w2p + (size_t)9 * 256 * 256;
    ushort_t* wofp = w3p + (size_t)1024 * 2 * 256;

    // 1) pack weights
    {
        int total = 256 * 1024 + 256 * 256 * 9 + 1024 * 256 + 9 * 32 * 256;
        pack_weights_kernel<<<(total + 255) / 256, 256, 0, stream>>>(
            w1, w2, w3, w_off, w1p, w2p, w3p, wofp);
    }
    // 2) r = relu(w1 . x + b1)    M=256, K=1024   (MFRAG=1: 784 blocks)
    {
        dim3 grid(HW / 64, CB / 64, N_);
        conv1x1_mfma_kernel<1, true, false><<<grid, 256, 0, stream>>>(
            w1p, x, b1, nullptr, r, CB, CIN);
    }
    // 3) offp[kh] = conv3x3(r[kh-quarter], w_off)  partials, K-split x4
    {
        dim3 grid(H_, 4, N_);
        offset_mfma_kernel<<<grid, 256, 0, stream>>>(r, wofp, offb);
    }
    // 4) r2 = relu(deform(r, sum(offp)+b_off) . w2 + b2)
    {
        deform_mfma_kernel<<<DBLK, 512, 0, stream>>>(
            r, offb, b_off, w2p, b2, r2);
    }
    // 5) out = relu(x + w3 . r2 + b3)   M=1024, K=256
    {
        dim3 grid(HW / 64, CIN / 128, N_);
        conv1x1_mfma_kernel<2, true, true><<<grid, 256, 0, stream>>>(
            w3p, r2, b3, x, out, CIN, CB);
    }
}

// Round 16
// 314.439 us; speedup vs baseline: 1.0538x; 1.0201x over previous
//
#include <hip/hip_runtime.h>
#include <hip/hip_bf16.h>

#define N_   4
#define CIN  1024
#define H_   56
#define W_   56
#define HW   3136
#define CB   256
#define KK   9
#define OFFC 18

typedef __attribute__((ext_vector_type(8))) short short8;
typedef __attribute__((ext_vector_type(4))) short short4v;
typedef __attribute__((ext_vector_type(4))) float float4v;
typedef unsigned short ushort_t;

// fp32 -> bf16 round-to-nearest-even
__device__ inline ushort_t bf16_rne(float f) {
    unsigned int u = __float_as_uint(f);
    unsigned int r = (u + 0x7FFFu + ((u >> 16) & 1u)) >> 16;
    return (ushort_t)r;
}
__device__ inline void split_bf16(float f, ushort_t& hi, ushort_t& lo) {
    ushort_t h = bf16_rne(f);
    float hf = __uint_as_float(((unsigned int)h) << 16);
    hi = h;
    lo = bf16_rne(f - hf);
}
__device__ inline short8 ld_frag_lds(const ushort_t* base) {
    short4v a = *(const short4v*)base;
    short4v b = *(const short4v*)(base + 4);
    return __builtin_shufflevector(a, b, 0, 1, 2, 3, 4, 5, 6, 7);
}
// Barrier that does NOT drain vmcnt (keeps prefetch global loads in flight).
__device__ inline void lds_barrier() {
    asm volatile("s_waitcnt lgkmcnt(0)" ::: "memory");
    __builtin_amdgcn_s_barrier();
    __builtin_amdgcn_sched_barrier(0);
}

// ---------------------------------------------------------------------------
// Pack weights.
// ---------------------------------------------------------------------------
__global__ void __launch_bounds__(256) pack_weights_kernel(
    const float* __restrict__ w1, const float* __restrict__ w2,
    const float* __restrict__ w3, const float* __restrict__ w_off,
    ushort_t* __restrict__ w1p, ushort_t* __restrict__ w2p,
    ushort_t* __restrict__ w3p, ushort_t* __restrict__ wofp)
{
    int e = blockIdx.x * 256 + threadIdx.x;
    if (e < 256 * 1024) {
        int o = e >> 10, k = e & 1023;
        ushort_t hi, lo; split_bf16(w1[e], hi, lo);
        w1p[(size_t)(o * 2 + 0) * 1024 + k] = hi;
        w1p[(size_t)(o * 2 + 1) * 1024 + k] = lo;
        return;
    }
    e -= 256 * 1024;
    if (e < 256 * 256 * 9) {
        int o = e / 2304; int rem = e % 2304; int c = rem / 9; int k = rem % 9;
        w2p[(size_t)(k * 256 + o) * 256 + c] = bf16_rne(w2[e]);
        return;
    }
    e -= 256 * 256 * 9;
    if (e < 1024 * 256) {
        int o = e >> 8, k = e & 255;
        ushort_t hi, lo; split_bf16(w3[e], hi, lo);
        w3p[(size_t)(o * 2 + 0) * 256 + k] = hi;
        w3p[(size_t)(o * 2 + 1) * 256 + k] = lo;
        return;
    }
    e -= 1024 * 256;
    if (e < 9 * 32 * 256) {
        int k = e / (32 * 256);
        int rem = e % (32 * 256);
        int m = rem >> 8, c = rem & 255;
        float v = (m < OFFC) ? w_off[((size_t)m * 256 + c) * 9 + k] : 0.f;
        wofp[e] = bf16_rne(v);
    }
}

// ---------------------------------------------------------------------------
// 1x1 conv via MFMA (round-11 verbatim).
// ---------------------------------------------------------------------------
template <int MFRAG, bool RELU, bool RESID>
__global__ void __launch_bounds__(256, 4) conv1x1_mfma_kernel(
    const ushort_t* __restrict__ Wp,   // [M][2][Kdim]
    const float* __restrict__ Xin,     // [n][Kdim][HW]
    const float* __restrict__ bias,    // [M]
    const float* __restrict__ resid,   // [n][M][HW] or null
    float* __restrict__ Cout,          // [n][M][HW]
    int M, int Kdim)
{
    __shared__ ushort_t Bs[64][36];   // [p][k], pad 36

    const int tid  = threadIdx.x;
    const int wave = tid >> 6;
    const int lane = tid & 63;
    const int l15  = lane & 15;
    const int quad = lane >> 4;
    const int pBase = blockIdx.x * 64;
    const int mBase = blockIdx.y * (MFRAG * 64) + wave * (MFRAG * 16);
    const int n     = blockIdx.z;
    const float* Xn = Xin + (size_t)n * Kdim * HW;

    float4v acc[MFRAG][4];
#pragma unroll
    for (int i = 0; i < MFRAG; ++i)
#pragma unroll
        for (int j = 0; j < 4; ++j) acc[i][j] = (float4v)(0.f);

    const int kk = tid >> 3;          // 0..31
    const int pq = (tid & 7) * 8;     // 0..56

    const float* src0 = &Xn[(size_t)kk * HW + pBase + pq];
    float4 c0 = *reinterpret_cast<const float4*>(src0);
    float4 c1 = *reinterpret_cast<const float4*>(src0 + 4);

    for (int k0 = 0; k0 < Kdim; k0 += 32) {
        lds_barrier();
        float vs[8] = {c0.x, c0.y, c0.z, c0.w, c1.x, c1.y, c1.z, c1.w};
#pragma unroll
        for (int j = 0; j < 8; ++j) Bs[pq + j][kk] = bf16_rne(vs[j]);

        short8 ah[MFRAG], al[MFRAG];
#pragma unroll
        for (int mt = 0; mt < MFRAG; ++mt) {
            const ushort_t* arow = Wp +
                ((size_t)(mBase + mt * 16 + l15) * 2) * Kdim + k0 + quad * 8;
            ah[mt] = *(const short8*)(arow);
            al[mt] = *(const short8*)(arow + Kdim);
        }
        if (k0 + 32 < Kdim) {
            const float* src = &Xn[(size_t)(k0 + 32 + kk) * HW + pBase + pq];
            c0 = *reinterpret_cast<const float4*>(src);
            c1 = *reinterpret_cast<const float4*>(src + 4);
        }
        lds_barrier();

        short8 bh[4];
#pragma unroll
        for (int nt = 0; nt < 4; ++nt)
            bh[nt] = ld_frag_lds(&Bs[nt * 16 + l15][quad * 8]);
        __builtin_amdgcn_s_setprio(1);
#pragma unroll
        for (int mt = 0; mt < MFRAG; ++mt)
#pragma unroll
            for (int nt = 0; nt < 4; ++nt) {
                acc[mt][nt] = __builtin_amdgcn_mfma_f32_16x16x32_bf16(
                    ah[mt], bh[nt], acc[mt][nt], 0, 0, 0);
                acc[mt][nt] = __builtin_amdgcn_mfma_f32_16x16x32_bf16(
                    al[mt], bh[nt], acc[mt][nt], 0, 0, 0);
            }
        __builtin_amdgcn_s_setprio(0);
    }

#pragma unroll
    for (int mt = 0; mt < MFRAG; ++mt)
#pragma unroll
        for (int rr = 0; rr < 4; ++rr) {
            int row = mBase + mt * 16 + quad * 4 + rr;
            float bv = bias[row];
#pragma unroll
            for (int nt = 0; nt < 4; ++nt) {
                int col = pBase + nt * 16 + l15;
                size_t idx = ((size_t)n * M + row) * HW + col;
                float v = acc[mt][nt][rr] + bv;
                if (RESID) v += resid[idx];
                if (RELU)  v = fmaxf(v, 0.f);
                Cout[idx] = v;
            }
        }
}

// ---------------------------------------------------------------------------
// Offset conv 3x3 via MFMA — v11 (round-11 verbatim): K-split by 4.
// ---------------------------------------------------------------------------
__global__ void __launch_bounds__(256, 2) offset_mfma_kernel(
    const float* __restrict__ r,        // [n][CB][HW]
    const ushort_t* __restrict__ wofp,  // [9][32][256] bf16
    float* __restrict__ offp)           // [4][n][18][HW] partials
{
    __shared__ float win[32][174];

    const int tid  = threadIdx.x;
    const int h    = blockIdx.x;
    const int kh   = blockIdx.y;
    const int n    = blockIdx.z;
    const int wave = tid >> 6;
    const int lane = tid & 63;
    const int l15  = lane & 15;
    const int quad = lane >> 4;
    const float* rn = r + (size_t)n * CB * HW;
    const int cb0 = kh * 64;

    const int p = wave * 16 + l15;

    float4v acc[2];
    acc[0] = (float4v)(0.f);
    acc[1] = (float4v)(0.f);

    for (int cb = cb0; cb < cb0 + 64; cb += 32) {
        __syncthreads();
        for (int f = tid; f < 32 * 3 * 14; f += 256) {
            int c = f / 42, remf = f % 42, row = remf / 14, x4 = (remf % 14) * 4;
            int yg = h - 1 + row;
            float4 v = {0.f, 0.f, 0.f, 0.f};
            if (yg >= 0 && yg < H_)
                v = *reinterpret_cast<const float4*>(
                    &rn[(size_t)(cb + c) * HW + yg * W_ + x4]);
            *reinterpret_cast<float4*>(&win[c][row * 56 + x4]) = v;
        }
        __syncthreads();

        short8 ahA0, ahA1, ahB0, ahB1;
        {
            const ushort_t* a0 = wofp + (size_t)(0 * 32 + l15) * 256 + cb + quad * 8;
            ahA0 = *(const short8*)a0;
            ahA1 = *(const short8*)(a0 + 16 * 256);
        }
#pragma unroll
        for (int k = 0; k < KK; ++k) {
            if (k + 1 < KK) {
                const ushort_t* a1 = wofp +
                    (size_t)((k + 1) * 32 + l15) * 256 + cb + quad * 8;
                ahB0 = *(const short8*)a1;
                ahB1 = *(const short8*)(a1 + 16 * 256);
            }
            const int ky = k / 3;
            const int dx = (k % 3) - 1;
            int x = p + dx;
            bool pvalid = (p < 56) && (x >= 0) && (x < 56);
            int xc = min(max(x, 0), 55);
            short8 bh;
#pragma unroll
            for (int j = 0; j < 8; ++j) {
                float v = win[quad * 8 + j][ky * 56 + xc];
                bh[j] = (short)bf16_rne(pvalid ? v : 0.f);
            }
            acc[0] = __builtin_amdgcn_mfma_f32_16x16x32_bf16(
                ahA0, bh, acc[0], 0, 0, 0);
            acc[1] = __builtin_amdgcn_mfma_f32_16x16x32_bf16(
                ahA1, bh, acc[1], 0, 0, 0);
            ahA0 = ahB0; ahA1 = ahB1;
        }
    }

    if (p < 56) {
        float* base = offp + (size_t)(kh * N_ + n) * OFFC * HW;
#pragma unroll
        for (int mt = 0; mt < 2; ++mt)
#pragma unroll
            for (int rr = 0; rr < 4; ++rr) {
                int m = mt * 16 + quad * 4 + rr;
                if (m < OFFC)
                    base[(size_t)m * HW + h * W_ + p] = acc[mt][rr];
            }
    }
}

// ---------------------------------------------------------------------------
// Deformable conv via MFMA — v13 (round-13 winner, FINAL): v8 merged
// build ∥ MFMA structure with b64 build gathers. CSTR=34 (row 136 B,
// 8B-aligned float2; bank base (2*bi+c)%32 -> ~2-way lane aliasing = free).
// Build per owner (288 owners, 32 ch): 16 iters x 4 independent float2
// corner reads + packed u32 Bs-write = 80 LDS ops (was 136 scalar).
// ---------------------------------------------------------------------------
#define TPX   28
#define WROWS 5
#define WCOLS 36
#define WPOS  (WROWS * WCOLS)   // 180
#define CSTR  34
#define WITEMS (32 * WROWS * 9) // 1440 float4 stage items per chunk
#define DBLK  (H_ * 2 * N_)     // 448
#define NCHUNK 8

__global__ void __launch_bounds__(512, 2) deform_mfma_kernel(
    const float* __restrict__ r,      // [n][CB][HW]
    const float* __restrict__ off,    // [4][n][18][HW] partials
    const float* __restrict__ b_off,  // [18]
    const ushort_t* __restrict__ w2p, // [9][256][256] bf16 hi
    const float* __restrict__ b2,
    float* __restrict__ r2)           // [n][CB][HW]
{
    __shared__ __align__(8) float    win[WPOS][CSTR];  // 24480 B
    __shared__ __align__(8) ushort_t Bs[2][KK][32][36];// 41472 B

    const int tid = threadIdx.x;
    const int bid = blockIdx.x;
    const int swz = (bid & 7) * (DBLK >> 3) + (bid >> 3);
    const int xh  = swz & 1;
    const int h   = (swz >> 1) % H_;
    const int n   = swz / (H_ * 2);
    const int xb  = xh * TPX;
    const float* rn = r + (size_t)n * CB * HW;

    // ---- per-thread build metadata in registers (tid < 288 owns (k,p)) ----
    int   bi0 = 0, bi1 = 0, bi2 = 0, bi3 = 0;
    float bw0 = 0.f, bw1 = 0.f, bw2 = 0.f, bw3 = 0.f;
    int   go0 = 0, go1 = 0, go2 = 0, go3 = 0;
    bool  bfast = true;
    const bool bactive = (tid < 288);
    const int  bk = bactive ? (tid / 32) : 0;
    const int  bp = bactive ? (tid % 32) : 0;
    if (bactive && bp < TPX) {
        int pg = xb + bp;
        size_t iy = (size_t)(2 * bk) * HW + h * W_ + pg;
        size_t ix = (size_t)(2 * bk + 1) * HW + h * W_ + pg;
        const size_t plane = (size_t)N_ * OFFC * HW;
        const float* o0 = off + (size_t)n * OFFC * HW;
        float dy = o0[iy] + o0[plane + iy] + o0[2 * plane + iy] +
                   o0[3 * plane + iy] + b_off[2 * bk];
        float dx = o0[ix] + o0[plane + ix] + o0[2 * plane + ix] +
                   o0[3 * plane + ix] + b_off[2 * bk + 1];
        float ys = (float)(h + (bk / 3) - 1) + dy;
        float xs = (float)(pg + (bk % 3) - 1) + dx;
        float y0f = floorf(ys), x0f = floorf(xs);
        int y0 = (int)y0f, x0 = (int)x0f;
        float wy1 = ys - y0f, wy0 = 1.f - wy1;
        float wx1 = xs - x0f, wx0 = 1.f - wx1;
        int   wid[4]; float wg[4]; int gof[4]; bool fast = true;
#pragma unroll
        for (int u = 0; u < 2; ++u)
#pragma unroll
            for (int vv = 0; vv < 2; ++vv) {
                int yy = y0 + u, xx = x0 + vv;
                bool valid = (yy >= 0) && (yy <= 55) && (xx >= 0) && (xx <= 55);
                float wgt = valid ? (u ? wy1 : wy0) * (vv ? wx1 : wx0) : 0.f;
                int ry = yy - (h - 2);
                int rx = xx - (xb - 4);
                if (wgt != 0.f &&
                    (ry < 0 || ry >= WROWS || rx < 0 || rx >= WCOLS))
                    fast = false;
                int idx = min(max(ry, 0), WROWS - 1) * WCOLS +
                          min(max(rx, 0), WCOLS - 1);
                wid[u * 2 + vv] = idx;
                wg[u * 2 + vv]  = wgt;
                gof[u * 2 + vv] = valid ? (yy * W_ + xx) : 0;
            }
        bfast = fast;
        bi0 = wid[0]; bi1 = wid[1]; bi2 = wid[2]; bi3 = wid[3];
        bw0 = wg[0];  bw1 = wg[1];  bw2 = wg[2];  bw3 = wg[3];
        go0 = gof[0]; go1 = gof[1]; go2 = gof[2]; go3 = gof[3];
    }

    const int wave = tid >> 6;
    const int lane = tid & 63;
    const int l15  = lane & 15;
    const int quad = lane >> 4;
    const int mW   = wave * 32;

    float4v acc[2][2];
#pragma unroll
    for (int i = 0; i < 2; ++i)
#pragma unroll
        for (int j = 0; j < 2; ++j) acc[i][j] = (float4v)(0.f);

    auto wload = [&](int f, int cbg) -> float4 {
        int c = f / 45, remf = f % 45, row = remf / 9, q = remf % 9;
        int yg = min(max(h - 2 + row, 0), H_ - 1);
        int xg = xb - 4 + q * 4;
        const float* src = &rn[(size_t)(cbg + c) * HW + yg * W_];
        float4 v;
        if (xg >= 0 && xg <= W_ - 4) {
            v = *reinterpret_cast<const float4*>(src + xg);
        } else {
            v.x = src[min(max(xg + 0, 0), W_ - 1)];
            v.y = src[min(max(xg + 1, 0), W_ - 1)];
            v.z = src[min(max(xg + 2, 0), W_ - 1)];
            v.w = src[min(max(xg + 3, 0), W_ - 1)];
        }
        return v;
    };
    auto wwrite = [&](float4* pre) {
#pragma unroll
        for (int i = 0; i < 3; ++i) {
            int f = tid + 512 * i;
            if (f < WITEMS) {
                int c = f / 45, remf = f % 45, row = remf / 9, q = remf % 9;
                int pos = row * WCOLS + q * 4;
                float4 v = pre[i];
                win[pos + 0][c] = v.x;
                win[pos + 1][c] = v.y;
                win[pos + 2][c] = v.z;
                win[pos + 3][c] = v.w;
            }
        }
    };
    // ---- build: b64 gathers, 2 channels per iter, 4 independent corners ----
    auto build = [&](int cbg, int pb) {
        if (bfast) {
#pragma unroll
            for (int c2 = 0; c2 < 32; c2 += 2) {
                float2 v0 = *(const float2*)&win[bi0][c2];
                float2 v1 = *(const float2*)&win[bi1][c2];
                float2 v2 = *(const float2*)&win[bi2][c2];
                float2 v3 = *(const float2*)&win[bi3][c2];
                float s0 = bw0 * v0.x + bw1 * v1.x + bw2 * v2.x + bw3 * v3.x;
                float s1 = bw0 * v0.y + bw1 * v1.y + bw2 * v2.y + bw3 * v3.y;
                unsigned int pk = (unsigned int)bf16_rne(s0) |
                                  ((unsigned int)bf16_rne(s1) << 16);
                *(unsigned int*)&Bs[pb][bk][bp][c2] = pk;
            }
        } else {
#pragma unroll
            for (int c4 = 0; c4 < 32; c4 += 4) {
                float s[4];
#pragma unroll
                for (int j = 0; j < 4; ++j) {
                    const float* rc = rn + (size_t)(cbg + c4 + j) * HW;
                    s[j] = bw0 * rc[go0] + bw1 * rc[go1] +
                           bw2 * rc[go2] + bw3 * rc[go3];
                }
                short4v pk;
#pragma unroll
                for (int j = 0; j < 4; ++j) pk[j] = (short)bf16_rne(s[j]);
                *(short4v*)&Bs[pb][bk][bp][c4] = pk;
            }
        }
    };

    // ---- prologue: stage + build chunk 0 ----
    float4 pre[3];
#pragma unroll
    for (int i = 0; i < 3; ++i) {
        int f = tid + 512 * i;
        if (f < WITEMS) pre[i] = wload(f, 0);
    }
    wwrite(pre);
#pragma unroll
    for (int i = 0; i < 3; ++i) {
        int f = tid + 512 * i;
        if (f < WITEMS) pre[i] = wload(f, 32);
    }
    lds_barrier();              // win(0) visible
    if (bactive) build(0, 0);
    lds_barrier();              // Bs[0] visible

    for (int ci = 0; ci < NCHUNK; ++ci) {
        const int cb = ci * 32;
        const bool hasNext = (ci + 1 < NCHUNK);
        if (hasNext) {
            wwrite(pre);        // win(ci+1); pre-data loaded 1 chunk ago
            if (ci + 2 < NCHUNK) {
#pragma unroll
                for (int i = 0; i < 3; ++i) {
                    int f = tid + 512 * i;
                    if (f < WITEMS) pre[i] = wload(f, cb + 64);
                }
            }
            lds_barrier();      // barA: win(ci+1) visible
            if (bactive) build(cb + 32, (ci + 1) & 1);
        }

        // ---- MFMA(ci) from Bs[ci&1], concurrent with build(ci+1) ----
        const ushort_t* bsb = &Bs[ci & 1][0][0][0];
        __builtin_amdgcn_s_setprio(1);
#pragma unroll
        for (int k = 0; k < KK; ++k) {
            short8 ah[2];
#pragma unroll
            for (int mt = 0; mt < 2; ++mt) {
                const ushort_t* arow = w2p +
                    (size_t)(k * 256 + (mW + mt * 16 + l15)) * 256 +
                    cb + quad * 8;
                ah[mt] = *(const short8*)(arow);
            }
            short8 bh[2];
#pragma unroll
            for (int nt = 0; nt < 2; ++nt)
                bh[nt] = ld_frag_lds(bsb + ((size_t)k * 32 +
                         nt * 16 + l15) * 36 + quad * 8);
#pragma unroll
            for (int mt = 0; mt < 2; ++mt)
#pragma unroll
                for (int nt = 0; nt < 2; ++nt)
                    acc[mt][nt] = __builtin_amdgcn_mfma_f32_16x16x32_bf16(
                        ah[mt], bh[nt], acc[mt][nt], 0, 0, 0);
        }
        __builtin_amdgcn_s_setprio(0);
        if (hasNext) lds_barrier();   // barB: build(ci+1) complete
    }

    // ---- epilogue: bias + relu ----
#pragma unroll
    for (int mt = 0; mt < 2; ++mt)
#pragma unroll
        for (int rr = 0; rr < 4; ++rr) {
            int o = mW + mt * 16 + quad * 4 + rr;
            float bv = b2[o];
#pragma unroll
            for (int nt = 0; nt < 2; ++nt) {
                int p = nt * 16 + l15;
                if (p < TPX) {
                    float v = fmaxf(acc[mt][nt][rr] + bv, 0.f);
                    r2[((size_t)n * CB + o) * HW + h * W_ + xb + p] = v;
                }
            }
        }
}

// ---------------------------------------------------------------------------
// kernel_launch
// ---------------------------------------------------------------------------
extern "C" void kernel_launch(void* const* d_in, const int* in_sizes, int n_in,
                              void* d_out, int out_size, void* d_ws, size_t ws_size,
                              hipStream_t stream)
{
    const float* x     = (const float*)d_in[0];
    const float* w1    = (const float*)d_in[1];
    const float* b1    = (const float*)d_in[2];
    const float* w_off = (const float*)d_in[3];
    const float* b_off = (const float*)d_in[4];
    const float* w2    = (const float*)d_in[5];
    const float* b2    = (const float*)d_in[6];
    const float* w3    = (const float*)d_in[7];
    const float* b3    = (const float*)d_in[8];
    float* out = (float*)d_out;

    float* ws  = (float*)d_ws;
    float* r    = ws;                             // 3,211,264 f
    float* r2   = r  + (size_t)N_ * CB * HW;      // 3,211,264 f
    float* offb = r2 + (size_t)N_ * CB * HW;      // 4 x 225,792 f (K-split)
    ushort_t* w1p  = (ushort_t*)(offb + (size_t)4 * N_ * OFFC * HW);
    ushort_t* w2p  = w1p + (size_t)256 * 2 * 1024;
    ushort_t* w3p  = w2p + (size_t)9 * 256 * 256;
    ushort_t* wofp = w3p + (size_t)1024 * 2 * 256;

    // 1) pack weights
    {
        int total = 256 * 1024 + 256 * 256 * 9 + 1024 * 256 + 9 * 32 * 256;
        pack_weights_kernel<<<(total + 255) / 256, 256, 0, stream>>>(
            w1, w2, w3, w_off, w1p, w2p, w3p, wofp);
    }
    // 2) r = relu(w1 . x + b1)    M=256, K=1024   (MFRAG=1: 784 blocks)
    {
        dim3 grid(HW / 64, CB / 64, N_);
        conv1x1_mfma_kernel<1, true, false><<<grid, 256, 0, stream>>>(
            w1p, x, b1, nullptr, r, CB, CIN);
    }
    // 3) offp[kh] = conv3x3(r[kh-quarter], w_off)  partials, K-split x4
    {
        dim3 grid(H_, 4, N_);
        offset_mfma_kernel<<<grid, 256, 0, stream>>>(r, wofp, offb);
    }
    // 4) r2 = relu(deform(r, sum(offp)+b_off) . w2 + b2)
    {
        deform_mfma_kernel<<<DBLK, 512, 0, stream>>>(
            r, offb, b_off, w2p, b2, r2);
    }
    // 5) out = relu(x + w3 . r2 + b3)   M=1024, K=256
    {
        dim3 grid(HW / 64, CIN / 128, N_);
        conv1x1_mfma_kernel<2, true, true><<<grid, 256, 0, stream>>>(
            w3p, r2, b3, x, out, CIN, CB);
    }
}